// Round 7
// baseline (103.391 us; speedup 1.0000x reference)
//
#include <hip/hip_runtime.h>

// Problem constants (match reference)
#define S    2048
#define H    16
#define TPB  256
#define MSTRIDE 4096             // padded length of per-head merged vector
#define PREP_SPLIT 16            // blocks per head in prep (256 blocks total)
#define SUPROWS 64               // rows per block (two 32-row passes)
#define NSUP (S / SUPROWS)       // 32 supertiles per matrix

typedef float f32x4 __attribute__((ext_vector_type(4)));

// out[bh, i, j] = e1[i-j, h] if i>=j else e2[j-i-1, h],  h = bh % 16.
// Reversed merged vector per head:
//   M[h][v] = e1[S-1-v, h]  for v <= S-1
//           = e2[v-S,   h]  for S <= v <= 2S-2, else 0
// then out[i, j] = M[h][(S-1) - i + j]  (row i reads M forward from S-1-i).

// Prep: 256 blocks (16 per head), 1 element per thread; latency-bound gather.
__global__ __launch_bounds__(TPB) void relpos_prep(
    const float* __restrict__ e1,   // (S, H)
    const float* __restrict__ e2,   // (S-1, H)
    float* __restrict__ M)          // (H, MSTRIDE)
{
    const int h    = blockIdx.x >> 4;            // / PREP_SPLIT
    const int part = blockIdx.x & (PREP_SPLIT - 1);
    const int v    = part * (MSTRIDE / PREP_SPLIT) + (int)threadIdx.x;
    float val = 0.0f;
    if (v <= S - 1)          val = e1[(S - 1 - v) * H + h];
    else if (v <= 2 * S - 2) val = e2[(v - S) * H + h];
    M[(size_t)h * MSTRIDE + v] = val;
}

// Main: 1024 blocks, each writes one 512 KiB strictly monotone stream
// (64 rows x 2048 cols) as two 32-row register-window passes.
__global__ __launch_bounds__(TPB) void relpos_main(
    const float* __restrict__ M,    // (H, MSTRIDE) in ws
    float* __restrict__ out)        // (2H, S, S)
{
    const int sup = blockIdx.x & (NSUP - 1);     // 0..31
    const int bh  = blockIdx.x >> 5;             // 0..31
    const int h   = bh & (H - 1);
    const int tid = threadIdx.x;

    const int ibase0 = sup * SUPROWS;
    const float* Mh  = M + (size_t)h * MSTRIDE;
    float* const o   = out + (size_t)bh * S * S + (size_t)ibase0 * S;
    const int j0 = tid * 4;

    #pragma unroll
    for (int p = 0; p < 2; ++p) {
        const int ibase = ibase0 + 32 * p;
        const int wb0   = (S - 1 - ibase) + j0 - 31;   // 4-aligned
        f32x4 w4[18];
        #pragma unroll
        for (int c = 0; c < 9; ++c) w4[c]     = *(const f32x4*)&Mh[wb0 + 4 * c];
        #pragma unroll
        for (int c = 0; c < 9; ++c) w4[9 + c] = *(const f32x4*)&Mh[wb0 + 1024 + 4 * c];
#define W0(t) w4[(t) >> 2][(t) & 3]
#define W1(t) w4[9 + ((t) >> 2)][(t) & 3]
        float* const op = o + (size_t)(32 * p) * S;
        #pragma unroll
        for (int r = 0; r < 32; ++r) {
            f32x4 a, b;
            a.x = W0(31 - r); a.y = W0(32 - r); a.z = W0(33 - r); a.w = W0(34 - r);
            b.x = W1(31 - r); b.y = W1(32 - r); b.z = W1(33 - r); b.w = W1(34 - r);
            *(f32x4*)(op + (size_t)r * S + j0)        = a;
            *(f32x4*)(op + (size_t)r * S + j0 + 1024) = b;
        }
#undef W0
#undef W1
    }
}

extern "C" void kernel_launch(void* const* d_in, const int* in_sizes, int n_in,
                              void* d_out, int out_size, void* d_ws, size_t ws_size,
                              hipStream_t stream) {
    // inputs: d_in[0] = q (unused), d_in[1] = e1 (S*H), d_in[2] = e2 ((S-1)*H)
    const float* e1 = (const float*)d_in[1];
    const float* e2 = (const float*)d_in[2];
    float* out = (float*)d_out;
    float* M   = (float*)d_ws;     // needs H*MSTRIDE*4 = 256 KiB

    relpos_prep<<<H * PREP_SPLIT, TPB, 0, stream>>>(e1, e2, M);
    relpos_main<<<2 * H * NSUP, TPB, 0, stream>>>(M, out);
}

// Round 8
// 99.273 us; speedup vs baseline: 1.0415x; 1.0415x over previous
//
#include <hip/hip_runtime.h>

// Problem constants (match reference)
#define S    2048
#define H    16
#define ROWS 32                  // rows per block
#define TPB  256
#define TILES_PER_H (S / ROWS)   // 64
#define MSTRIDE 4096             // padded length of per-head merged vector
#define PREP_SPLIT 16            // blocks per head in prep (256 blocks total)

typedef float f32x4 __attribute__((ext_vector_type(4)));

// out[bh, i, j] = e1[i-j, h] if i>=j else e2[j-i-1, h],  h = bh % 16.
// Reversed merged vector per head:
//   M[h][v] = e1[S-1-v, h]  for v <= S-1
//           = e2[v-S,   h]  for S <= v <= 2S-2, else 0
// then out[i, j] = M[h][(S-1) - i + j]  (row i reads M forward from S-1-i).

// Prep: 256 blocks (16 per head), 1 element per thread; latency-bound gather.
__global__ __launch_bounds__(TPB) void relpos_prep(
    const float* __restrict__ e1,   // (S, H)
    const float* __restrict__ e2,   // (S-1, H)
    float* __restrict__ M)          // (H, MSTRIDE)
{
    const int h    = blockIdx.x >> 4;            // / PREP_SPLIT
    const int part = blockIdx.x & (PREP_SPLIT - 1);
    const int v    = part * (MSTRIDE / PREP_SPLIT) + (int)threadIdx.x;
    float val = 0.0f;
    if (v <= S - 1)          val = e1[(S - 1 - v) * H + h];
    else if (v <= 2 * S - 2) val = e2[(v - S) * H + h];
    M[(size_t)h * MSTRIDE + v] = val;
}

// Main: 2048 blocks; each writes one strictly monotone contiguous 256 KiB
// stream (32 rows x 2048 cols) from statically-indexed register windows
// loaded directly from the L2-resident M (256 KiB total).
__global__ __launch_bounds__(TPB) void relpos_main(
    const float* __restrict__ M,    // (H, MSTRIDE) in ws
    float* __restrict__ out)        // (2H, S, S)
{
    const int tile = blockIdx.x & (TILES_PER_H - 1);
    const int bh   = blockIdx.x >> 6;            // 0..31
    const int h    = bh & (H - 1);
    const int tid  = threadIdx.x;

    const int ibase = tile * ROWS;
    const float* Mh = M + (size_t)h * MSTRIDE;
    float* const o  = out + (size_t)bh * S * S + (size_t)ibase * S;

    // Preload BOTH column-half windows (statically indexed -> registers).
    const int j0  = tid * 4;
    const int wb0 = (S - 1 - ibase) + j0 - 31;   // 4-aligned, in [0, 3036]
    f32x4 w4[18];
    #pragma unroll
    for (int c = 0; c < 9; ++c) w4[c]     = *(const f32x4*)&Mh[wb0 + 4 * c];
    #pragma unroll
    for (int c = 0; c < 9; ++c) w4[9 + c] = *(const f32x4*)&Mh[wb0 + 1024 + 4 * c];
#define W0(t) w4[(t) >> 2][(t) & 3]
#define W1(t) w4[9 + ((t) >> 2)][(t) & 3]
    // r-outer: block writes rows in order; within a row, half0 then half1
    // -> one monotone contiguous 256 KiB stream.
    #pragma unroll
    for (int r = 0; r < ROWS; ++r) {
        f32x4 a, b;
        a.x = W0(31 - r); a.y = W0(32 - r); a.z = W0(33 - r); a.w = W0(34 - r);
        b.x = W1(31 - r); b.y = W1(32 - r); b.z = W1(33 - r); b.w = W1(34 - r);
        *(f32x4*)(o + (size_t)r * S + j0)        = a;
        *(f32x4*)(o + (size_t)r * S + j0 + 1024) = b;
    }
#undef W0
#undef W1
}

extern "C" void kernel_launch(void* const* d_in, const int* in_sizes, int n_in,
                              void* d_out, int out_size, void* d_ws, size_t ws_size,
                              hipStream_t stream) {
    // inputs: d_in[0] = q (unused), d_in[1] = e1 (S*H), d_in[2] = e2 ((S-1)*H)
    const float* e1 = (const float*)d_in[1];
    const float* e2 = (const float*)d_in[2];
    float* out = (float*)d_out;
    float* M   = (float*)d_ws;     // needs H*MSTRIDE*4 = 256 KiB

    relpos_prep<<<H * PREP_SPLIT, TPB, 0, stream>>>(e1, e2, M);
    relpos_main<<<2 * H * TILES_PER_H, TPB, 0, stream>>>(M, out);
}